// Round 1
// baseline (383.576 us; speedup 1.0000x reference)
//
#include <hip/hip_runtime.h>
#include <math.h>

#define V55 55
#define T128 128
#define BT 16
#define ATP 68          // AT row pitch in floats (272 B: 16B-aligned, bank-friendly)
#define GP 65           // g row pitch in floats (breaks d-major bank conflicts)
#define GSLOT (V55*GP)  // 3575

__global__ __launch_bounds__(256, 2)
void shiftgcn_fused(const float* __restrict__ x,
                    const float* __restrict__ Wm,
                    const float* __restrict__ bvec,
                    const float* __restrict__ fm,
                    const float* __restrict__ bn1g, const float* __restrict__ bn1b,
                    const float* __restrict__ bn1m, const float* __restrict__ bn1v,
                    const float* __restrict__ bn2g, const float* __restrict__ bn2b,
                    const float* __restrict__ bn2m, const float* __restrict__ bn2v,
                    float* __restrict__ out)
{
    __shared__ __align__(16) float AT[V55 * ATP];   // masked, node-shifted, transposed A-tile
    __shared__ __align__(16) float g[3 * GSLOT];    // rolling ring of spatial-stage outputs

    const int tid = threadIdx.x;
    const int n   = blockIdx.x >> 3;          // 64 batches
    const int t0  = (blockIdx.x & 7) * BT;    // 8 t-tiles of 16

    // ---------------- GEMM-role coords: d = lane, wave = v-group ----------------
    const int d  = tid & 63;
    const int vg = tid >> 6;
    const int vstart = vg * 14;
    const int NV = (vg < 3) ? 14 : 13;        // 55 = 14+14+14+13

    float Wreg[64];
    #pragma unroll
    for (int c = 0; c < 64; ++c) Wreg[c] = Wm[c * 64 + d];   // coalesced: lanes = d

    // BN1 folded (scale/shift), +b folded into shift
    float s1[14], sh1[14];
    #pragma unroll
    for (int k = 0; k < 14; ++k) {
        int v = vstart + k;
        int j = (v < V55 ? v : 0) * 64 + d;
        float sc = bn1g[j] * rsqrtf(bn1v[j] + 1e-5f);
        s1[k]  = sc;
        sh1[k] = bn1b[j] - bn1m[j] * sc + sc * bvec[d];
    }

    // ---------------- output-role coords: lanes = v (coalesced global) ----------
    const int v_o = tid & 63;                 // active when < 55
    const int d_o = tid >> 6;
    float s2r[16], sh2r[16];
    #pragma unroll
    for (int kk = 0; kk < 16; ++kk) {
        int dd = kk * 4 + d_o;
        float sc = bn2g[dd] * rsqrtf(bn2v[dd] + 1e-5f);
        s2r[kk]  = sc;
        sh2r[kk] = bn2b[dd] - bn2m[dd] * sc;
    }
    const int ro = d_o % 3;                   // (4kk+d_o)%3 == (kk+d_o)%3

    // ---------------- staging coords: lane -> (c4, vb) -------------------------
    const int c4 = tid & 3;
    const int vb = tid >> 2;                  // source node; active when < 55
    const bool stage_act = (vb < V55);
    int v0_init = vb - c4; if (v0_init < 0) v0_init += V55;

    float msr[16];                            // mask factors, constant over t
    if (stage_act) {
        int v = v0_init;
        #pragma unroll
        for (int j = 0; j < 16; ++j) {
            int c = 4 * j + c4;
            msr[j] = tanhf(fm[v * 64 + c]) + 1.0f;
            v -= 4; if (v < 0) v += V55;
        }
    }

    const int xbase_n = n * (64 * T128 * V55);

    for (int t = t0 - 1; t <= t0 + BT; ++t) {
        // ---------------- stage AT(t): gather + mask + transpose ----------------
        if ((unsigned)t < (unsigned)T128 && stage_act) {
            float xvr[16];
            #pragma unroll
            for (int j = 0; j < 16; ++j) {
                int c = 4 * j + c4;
                xvr[j] = x[xbase_n + (c * T128 + t) * V55 + vb];  // 4x64B segments/wave
            }
            int v = v0_init;
            #pragma unroll
            for (int j = 0; j < 16; ++j) {
                int c = 4 * j + c4;
                AT[v * ATP + c] = xvr[j] * msr[j];   // 2-way banks max (free)
                v -= 4; if (v < 0) v += V55;
            }
        }
        __syncthreads();

        // ---------------- GEMM 55x64x64 + BN1 + inverse shift + relu -> g -------
        if ((unsigned)t < (unsigned)T128) {
            const int slot = t % 3;
            float* gs = g + slot * GSLOT;
            #pragma unroll
            for (int k = 0; k < 14; ++k) {
                if (k < NV) {
                    const int v = vstart + k;
                    const float4* Arow = (const float4*)(AT + v * ATP);
                    float ax = 0.f, ay = 0.f, az = 0.f, aw = 0.f;
                    #pragma unroll
                    for (int q = 0; q < 16; ++q) {
                        float4 a4 = Arow[q];          // wave-uniform broadcast read
                        ax = fmaf(a4.x, Wreg[4*q+0], ax);
                        ay = fmaf(a4.y, Wreg[4*q+1], ay);
                        az = fmaf(a4.z, Wreg[4*q+2], az);
                        aw = fmaf(a4.w, Wreg[4*q+3], aw);
                    }
                    float a = (ax + ay) + (az + aw);
                    float r = fmaxf(fmaf(s1[k], a, sh1[k]), 0.f);
                    int vout = v + d;                 // inverse spatial shift
                    if (vout >= V55) vout -= V55;
                    if (vout >= V55) vout -= V55;
                    gs[vout * GP + d] = r;
                }
            }
        }
        __syncthreads();

        // ---------------- emit t_out = t-1: temporal shift + BN2 + residual -----
        const int t_out = t - 1;
        if (t_out >= t0 && t_out < t0 + BT && v_o < V55) {
            int sl_t  = t % 3;                       // t >= 1 here
            int sl_m1 = sl_t - 1; if (sl_m1 < 0) sl_m1 += 3;
            int sl_m2 = sl_t - 2; if (sl_m2 < 0) sl_m2 += 3;
            #pragma unroll
            for (int kk = 0; kk < 16; ++kk) {
                int dd = kk * 4 + d_o;
                int rk = (kk % 3) + ro; if (rk >= 3) rk -= 3;   // dd%3
                int tsrc = t_out + rk - 1;
                int slot_src = (rk == 0) ? sl_m2 : ((rk == 1) ? sl_m1 : sl_t);
                float gv = 0.f;
                if ((unsigned)tsrc < (unsigned)T128)
                    gv = g[slot_src * GSLOT + v_o * GP + dd];
                float val = fmaf(s2r[kk], gv, sh2r[kk]);
                int oidx = xbase_n + (dd * T128 + t_out) * V55 + v_o;
                float xres = x[oidx];                // L2-hot: same slice staged @ t_out
                out[oidx] = fmaxf(val + xres, 0.f);
            }
        }
    }
}

extern "C" void kernel_launch(void* const* d_in, const int* in_sizes, int n_in,
                              void* d_out, int out_size, void* d_ws, size_t ws_size,
                              hipStream_t stream) {
    const float* x    = (const float*)d_in[0];
    const float* Wm   = (const float*)d_in[1];
    const float* bvec = (const float*)d_in[2];
    const float* fm   = (const float*)d_in[3];
    const float* bn1g = (const float*)d_in[4];
    const float* bn1b = (const float*)d_in[5];
    const float* bn1m = (const float*)d_in[6];
    const float* bn1v = (const float*)d_in[7];
    const float* bn2g = (const float*)d_in[8];
    const float* bn2b = (const float*)d_in[9];
    const float* bn2m = (const float*)d_in[10];
    const float* bn2v = (const float*)d_in[11];
    float* out = (float*)d_out;

    shiftgcn_fused<<<dim3(64 * 8), dim3(256), 0, stream>>>(
        x, Wm, bvec, fm, bn1g, bn1b, bn1m, bn1v, bn2g, bn2b, bn2m, bn2v, out);
}